// Round 5
// baseline (1253.867 us; speedup 1.0000x reference)
//
#include <hip/hip_runtime.h>

#define NTOK 65536
#define DIMD 256
#define VOC  1024
#define NLEV 4
#define TAU  0.045f   // screened top-2 gap below this -> exact numpy-fp32 rescan

typedef __attribute__((ext_vector_type(8))) _Float16 f16x8;
typedef __attribute__((ext_vector_type(4))) float f32x4;

// ---------------------------------------------------------------------------
// ws layout:
//   [0]        double loss_acc ; [8] int ambig_count
//   [16]       float  wnorm[NLEV][VOC]        (16 KB)
//   [16400]    float  rnorm[NTOK]             (256 KB)
//   [278544]   int    idx[NLEV][NTOK]         (1 MB)
//   [1327120]  int    ambig_list[NTOK]        (256 KB)
//   [1589264]  uint4  wimg[NLEV*64*512]       (2 MB)  f16 pre-swizzled W
//   [3686416]  uint4  aimg[512*8*512]         (32 MB) f16 pre-swizzled residual
// residual fp32 lives in d_out[1:] until k_final_out rewrites it.
// Image chunk = 128 rows x 32 k (f16): 512 uint4; row r holds 4 granules of
// 8 f16, granule ko stored at position ko ^ (r&3) ^ ((r>>2)&3).
// ---------------------------------------------------------------------------

__device__ __forceinline__ int swz4(int ko, int r) {
    return ko ^ (r & 3) ^ ((r >> 2) & 3);
}

__device__ __forceinline__ uint4 cvt8_f16(const float4 x0, const float4 x1) {
    union { f16x8 h; uint4 u; } r;
    r.h[0] = (_Float16)x0.x; r.h[1] = (_Float16)x0.y;
    r.h[2] = (_Float16)x0.z; r.h[3] = (_Float16)x0.w;
    r.h[4] = (_Float16)x1.x; r.h[5] = (_Float16)x1.y;
    r.h[6] = (_Float16)x1.z; r.h[7] = (_Float16)x1.w;
    return r.u;
}

__device__ __forceinline__ void gl_lds16(const uint4* g, uint4* l) {
    __builtin_amdgcn_global_load_lds(
        (const __attribute__((address_space(1))) unsigned*)g,
        (__attribute__((address_space(3))) unsigned*)l, 16, 0, 0);
}

// write 4 residual floats (lane-major float4 layout, d = lane*4..+3) into the
// f16 image for token t
__device__ __forceinline__ void store_img4(uint4* aimg, int t, int lane, float4 v) {
    union { _Float16 h[4]; uint2 u; } p;
    p.h[0] = (_Float16)v.x; p.h[1] = (_Float16)v.y;
    p.h[2] = (_Float16)v.z; p.h[3] = (_Float16)v.w;
    const int r  = t & 127;
    const int dc = lane >> 3, ko = (lane >> 1) & 3, hf = lane & 1;
    uint2* dst = (uint2*)(aimg + ((size_t)(t >> 7) * 8 + dc) * 512
                          + r * 4 + swz4(ko, r)) + hf;
    *dst = p.u;
}

// ------------------- pre-convert + pre-swizzle W ---------------------------
__global__ void k_wsplit(const float* __restrict__ emb, uint4* __restrict__ wimg,
                         int* ambig_count)
{
    if (blockIdx.x == 0 && threadIdx.x == 0) *ambig_count = 0;
    const int chunk = blockIdx.x;          // 256: l*64 + cb*8 + dc
    const int l = chunk >> 6, cb = (chunk >> 3) & 7, dc = chunk & 7;
    #pragma unroll
    for (int i = 0; i < 2; ++i) {
        const int s = threadIdx.x + i * 256;   // 0..511
        const int r = s >> 2, ko = s & 3;
        const float* src = emb + ((size_t)(l * VOC + cb * 128 + r)) * DIMD + dc * 32 + ko * 8;
        const float4 x0 = *reinterpret_cast<const float4*>(src);
        const float4 x1 = *reinterpret_cast<const float4*>(src + 4);
        wimg[(size_t)chunk * 512 + r * 4 + swz4(ko, r)] = cvt8_f16(x0, x1);
    }
}

// ------------------- numpy pairwise sum-of-squares -------------------------
__device__ __forceinline__ float np_pairnorm_row(const float* row, int j)
{
#pragma clang fp contract(off)
    const int half = j >> 3;
    const int jj   = j & 7;
    const float* a = row + half * 128 + jj;
    float r = a[0] * a[0];
    #pragma unroll
    for (int i = 1; i < 16; ++i) {
        const float x  = a[8 * i];
        const float sq = x * x;
        r = r + sq;
    }
    r = r + __shfl_xor(r, 1);
    r = r + __shfl_xor(r, 2);
    r = r + __shfl_xor(r, 4);
    r = r + __shfl_xor(r, 8);
    return r;
}

__global__ void k_pairnorm(const float* src, float* __restrict__ dst,
                           int nrows, double* loss_acc)
{
    if (loss_acc && blockIdx.x == 0 && threadIdx.x == 0) *loss_acc = 0.0;
    const int gtid  = blockIdx.x * blockDim.x + threadIdx.x;
    const int gwave = gtid >> 6;
    const int lane  = threadIdx.x & 63;
    const int nwave = (gridDim.x * blockDim.x) >> 6;
    const int sub   = lane >> 4;
    const int j     = lane & 15;
    for (int r4 = gwave; r4 * 4 < nrows; r4 += nwave) {
        const int row = r4 * 4 + sub;
        const float v = np_pairnorm_row(src + (size_t)row * DIMD, j);
        if (j == 0) dst[row] = v;
    }
}

// ---- level-0: latent -> aimg (optional) + approx rnorm ---------------------
__global__ void k_rsplit0(const float* __restrict__ latent, uint4* __restrict__ aimg,
                          float* __restrict__ rnorm, int write_img)
{
    const int gtid = blockIdx.x * blockDim.x + threadIdx.x;
    const int gw   = gtid >> 6, lane = threadIdx.x & 63;
    const int nw   = (gridDim.x * blockDim.x) >> 6;
    for (int t = gw; t < NTOK; t += nw) {
        const float4 v = reinterpret_cast<const float4*>(latent + (size_t)t * DIMD)[lane];
        float s4 = v.x * v.x + v.y * v.y + v.z * v.z + v.w * v.w;
        #pragma unroll
        for (int off = 32; off; off >>= 1) s4 += __shfl_xor(s4, off);
        if (lane == 0) rnorm[t] = s4;
        if (write_img) store_img4(aimg, t, lane, v);
    }
}

// on-the-fly A conversion for the no-image fallback path
__device__ __forceinline__ void stageA_fly(const float* rsrc, int tok0, int dn,
                                           uint4* dst, int tid)
{
    #pragma unroll
    for (int i = 0; i < 2; ++i) {
        const int s = tid + i * 256, r = s >> 2, ko = s & 3;
        const float* g = rsrc + (size_t)(tok0 + r) * DIMD + dn * 32 + ko * 8;
        dst[r * 4 + swz4(ko, r)] =
            cvt8_f16(*reinterpret_cast<const float4*>(g),
                     *reinterpret_cast<const float4*>(g + 4));
    }
}

// ------------------- f16 MFMA screen (single pass, top-2) -------------------
template<int PRESPLIT>
__global__ __launch_bounds__(256, 2)
void k_screen(const float* rsrc, const uint4* __restrict__ aimg,
              const uint4* __restrict__ wimg_l,
              const float* __restrict__ rnorm, const float* __restrict__ wnorml,
              int* __restrict__ idxl, int* __restrict__ ambig_list,
              int* __restrict__ ambig_count)
{
    __shared__ uint4 ldsA[2][512];   // 16 KB
    __shared__ uint4 ldsB[2][512];   // 16 KB
    __shared__ float tM1[128][2], tM2[128][2];
    __shared__ int   tI1[128][2];

    const int tid = threadIdx.x, lane = tid & 63, w = tid >> 6;
    const int wm = w >> 1, wn = w & 1;
    const int lr = lane & 15, lg = lane >> 4;
    const int tok0 = blockIdx.x * 128;
    const uint4* ablk = aimg + (size_t)blockIdx.x * (8 * 512);

    float rn[4][4];
    #pragma unroll
    for (int m = 0; m < 4; ++m)
        #pragma unroll
        for (int r = 0; r < 4; ++r)
            rn[m][r] = rnorm[tok0 + wm * 64 + m * 16 + lg * 4 + r];

    float m1[4][4], m2[4][4]; int i1[4][4];
    #pragma unroll
    for (int m = 0; m < 4; ++m)
        #pragma unroll
        for (int r = 0; r < 4; ++r) { m1[m][r] = 3.0e38f; m2[m][r] = 3.0e38f; i1[m][r] = 0; }

    f32x4 acc[4][4];

    // prologue: stage phase 0
    if (PRESPLIT) { gl_lds16(ablk + tid, &ldsA[0][tid]); gl_lds16(ablk + tid + 256, &ldsA[0][tid + 256]); }
    else          stageA_fly(rsrc, tok0, 0, &ldsA[0][0], tid);
    gl_lds16(wimg_l + tid, &ldsB[0][tid]);
    gl_lds16(wimg_l + tid + 256, &ldsB[0][tid + 256]);
    __syncthreads();

    for (int p = 0; p < 64; ++p) {
        const int cur = p & 1, nxt = cur ^ 1;
        const int ct = p >> 3, dc = p & 7;
        if (p < 63) {   // stage next phase (flies during compute)
            const int dn = (p + 1) & 7;
            if (PRESPLIT) {
                const uint4* src = ablk + (size_t)dn * 512;
                gl_lds16(src + tid, &ldsA[nxt][tid]);
                gl_lds16(src + tid + 256, &ldsA[nxt][tid + 256]);
            } else {
                stageA_fly(rsrc, tok0, dn, &ldsA[nxt][0], tid);
            }
            const uint4* bs = wimg_l + (size_t)(p + 1) * 512;
            gl_lds16(bs + tid, &ldsB[nxt][tid]);
            gl_lds16(bs + tid + 256, &ldsB[nxt][tid + 256]);
        }
        if (dc == 0) {
            #pragma unroll
            for (int m = 0; m < 4; ++m)
                #pragma unroll
                for (int n = 0; n < 4; ++n) acc[m][n] = (f32x4)0.0f;
        }
        f16x8 af[4];
        #pragma unroll
        for (int m = 0; m < 4; ++m) {
            const int r = wm * 64 + m * 16 + lr;
            af[m] = *reinterpret_cast<const f16x8*>(&ldsA[cur][r * 4 + swz4(lg, r)]);
        }
        #pragma unroll
        for (int n = 0; n < 4; ++n) {
            const int rb = wn * 64 + n * 16 + lr;
            const f16x8 bf = *reinterpret_cast<const f16x8*>(&ldsB[cur][rb * 4 + swz4(lg, rb)]);
            #pragma unroll
            for (int m = 0; m < 4; ++m)
                acc[m][n] = __builtin_amdgcn_mfma_f32_16x16x32_f16(af[m], bf, acc[m][n], 0, 0, 0);
        }
        if (dc == 7) {   // finish this 128-code tile: top-2 update
            #pragma unroll
            for (int n = 0; n < 4; ++n) {
                const int c = ct * 128 + wn * 64 + n * 16 + lr;
                const float wnv = wnorml[c];
                #pragma unroll
                for (int m = 0; m < 4; ++m)
                    #pragma unroll
                    for (int r = 0; r < 4; ++r) {
                        const float s = fmaf(-2.0f, acc[m][n][r], rn[m][r]) + wnv;
                        if (s < m1[m][r]) { m2[m][r] = m1[m][r]; m1[m][r] = s; i1[m][r] = c; }
                        else if (s < m2[m][r]) { m2[m][r] = s; }
                    }
            }
        }
        __syncthreads();
    }

    // butterfly merge across the 16 col-lanes, then LDS cross-wave merge
    #pragma unroll
    for (int m = 0; m < 4; ++m)
        #pragma unroll
        for (int r = 0; r < 4; ++r) {
            float a1 = m1[m][r], a2 = m2[m][r]; int ai = i1[m][r];
            #pragma unroll
            for (int d = 1; d < 16; d <<= 1) {
                const float o1 = __shfl_xor(a1, d);
                const float o2 = __shfl_xor(a2, d);
                const int   oi = __shfl_xor(ai, d);
                if (o1 < a1 || (o1 == a1 && oi < ai)) { a2 = fminf(a1, o2); a1 = o1; ai = oi; }
                else { a2 = fminf(a2, fminf(o1, o2)); }
            }
            if (lr == 0) {
                const int t = wm * 64 + m * 16 + lg * 4 + r;
                tM1[t][wn] = a1; tM2[t][wn] = a2; tI1[t][wn] = ai;
            }
        }
    __syncthreads();
    if (tid < 128) {
        float a1 = tM1[tid][0], a2 = tM2[tid][0]; int ai = tI1[tid][0];
        const float o1 = tM1[tid][1], o2 = tM2[tid][1]; const int oi = tI1[tid][1];
        if (o1 < a1 || (o1 == a1 && oi < ai)) { a2 = fminf(a1, o2); a1 = o1; ai = oi; }
        else { a2 = fminf(a2, fminf(o1, o2)); }
        const int gt = tok0 + tid;
        idxl[gt] = ai;
        if (a2 - a1 < TAU) {
            const int p = atomicAdd(ambig_count, 1);
            ambig_list[p] = gt;
        }
    }
}

// ---------------- exact numpy-fp32 rescan for ambiguous tokens --------------
__global__ void k_rescue(const float* rsrc, const float* __restrict__ embl,
                         const float* __restrict__ wnorml,
                         const int* __restrict__ ambig_list, const int* __restrict__ ambig_count,
                         int* __restrict__ idxl)
{
    __shared__ float rbuf[DIMD];
    const int lane = threadIdx.x;   // blockDim.x == 64
    int cnt = *ambig_count; if (cnt > NTOK) cnt = NTOK;
    for (int k = blockIdx.x; k < cnt; k += gridDim.x) {
        const int t = ambig_list[k];
        reinterpret_cast<float4*>(rbuf)[lane] =
            reinterpret_cast<const float4*>(rsrc + (size_t)t * DIMD)[lane];
        __syncthreads();
        const float rnv = np_pairnorm_row(rbuf, lane & 15);   // exact numpy rnorm
        float best = 3.0e38f; int besti = 0x7fffffff;
        for (int j = 0; j < 16; ++j) {
            const int c = j * 64 + lane;
            const float* wr = embl + (size_t)c * DIMD;
            float acc = 0.0f;
            for (int d = 0; d < DIMD; d += 4) {   // sequential fmaf, d ascending
                const float4 wv = *reinterpret_cast<const float4*>(wr + d);
                acc = fmaf(rbuf[d + 0], wv.x, acc);
                acc = fmaf(rbuf[d + 1], wv.y, acc);
                acc = fmaf(rbuf[d + 2], wv.z, acc);
                acc = fmaf(rbuf[d + 3], wv.w, acc);
            }
            const float s = fmaf(-2.0f, acc, rnv) + wnorml[c];  // numpy two-rounding
            if (s < best || (s == best && c < besti)) { best = s; besti = c; }
        }
        #pragma unroll
        for (int off = 32; off > 0; off >>= 1) {
            const float ov = __shfl_down(best, off);
            const int   oi = __shfl_down(besti, off);
            if (ov < best || (ov == best && oi < besti)) { best = ov; besti = oi; }
        }
        if (lane == 0) idxl[t] = besti;
        __syncthreads();
    }
}

// ---- fused: gather code; loss; residual fp32; f16 image; approx rnorm ------
// mode bit0: write res + rnorm (levels 0..2); bit1: write aimg
__global__ void k_update(const float* rsrc, float* res, uint4* __restrict__ aimg,
                         const float* embl, const int* __restrict__ idxl,
                         float* __restrict__ rnorm_out,
                         double* loss_acc, int* ambig_count, int mode)
{
    if (blockIdx.x == 0 && threadIdx.x == 0) *ambig_count = 0;
    const int gtid = blockIdx.x * blockDim.x + threadIdx.x;
    const int gw   = gtid >> 6, lane = threadIdx.x & 63;
    const int nw   = (gridDim.x * blockDim.x) >> 6;
    float lsum = 0.0f;
    for (int t = gw; t < NTOK; t += nw) {
        const int ci = idxl[t];
        const float4 q = reinterpret_cast<const float4*>(embl + (size_t)ci * DIMD)[lane];
        const float4 r = reinterpret_cast<const float4*>(rsrc + (size_t)t * DIMD)[lane];
        float4 nr;
        nr.x = r.x - q.x; nr.y = r.y - q.y; nr.z = r.z - q.z; nr.w = r.w - q.w;
        const float s4 = nr.x * nr.x + nr.y * nr.y + nr.z * nr.z + nr.w * nr.w;
        lsum += s4;
        if (mode & 1) {
            reinterpret_cast<float4*>(res + (size_t)t * DIMD)[lane] = nr;
            float tk = s4;
            #pragma unroll
            for (int off = 32; off; off >>= 1) tk += __shfl_xor(tk, off);
            if (lane == 0) rnorm_out[t] = tk;
        }
        if (mode & 2) store_img4(aimg, t, lane, nr);
    }
    #pragma unroll
    for (int off = 32; off > 0; off >>= 1) lsum += __shfl_down(lsum, off);
    if (lane == 0) atomicAdd(loss_acc, (double)lsum);
}

__global__ void k_final_out(const float* __restrict__ latent, const float* __restrict__ emb,
                            const int* __restrict__ idx, float* outq)
{
    const int gtid  = blockIdx.x * blockDim.x + threadIdx.x;
    const int gwave = gtid >> 6;
    const int lane  = threadIdx.x & 63;
    const int nwave = (gridDim.x * blockDim.x) >> 6;
    for (int t = gwave; t < NTOK; t += nwave) {
        const float4 q0 = reinterpret_cast<const float4*>(
            emb + ((size_t)0 * VOC + idx[0 * NTOK + t]) * DIMD)[lane];
        const float4 q1 = reinterpret_cast<const float4*>(
            emb + ((size_t)1 * VOC + idx[1 * NTOK + t]) * DIMD)[lane];
        const float4 q2 = reinterpret_cast<const float4*>(
            emb + ((size_t)2 * VOC + idx[2 * NTOK + t]) * DIMD)[lane];
        const float4 q3 = reinterpret_cast<const float4*>(
            emb + ((size_t)3 * VOC + idx[3 * NTOK + t]) * DIMD)[lane];
        const float4 l4 = reinterpret_cast<const float4*>(latent + (size_t)t * DIMD)[lane];
        float4 o;
        { float c = q0.x; c = c + q1.x; c = c + q2.x; c = c + q3.x; o.x = l4.x + (c - l4.x); }
        { float c = q0.y; c = c + q1.y; c = c + q2.y; c = c + q3.y; o.y = l4.y + (c - l4.y); }
        { float c = q0.z; c = c + q1.z; c = c + q2.z; c = c + q3.z; o.z = l4.z + (c - l4.z); }
        { float c = q0.w; c = c + q1.w; c = c + q2.w; c = c + q3.w; o.w = l4.w + (c - l4.w); }
        reinterpret_cast<float4*>(outq + (size_t)t * DIMD)[lane] = o;
    }
}

__global__ void k_loss_final(const double* __restrict__ loss_acc, float* __restrict__ out0)
{
    *out0 = (float)(1.25 * (*loss_acc) / ((double)NTOK * (double)DIMD));
}

extern "C" void kernel_launch(void* const* d_in, const int* in_sizes, int n_in,
                              void* d_out, int out_size, void* d_ws, size_t ws_size,
                              hipStream_t stream)
{
    const float* latent = (const float*)d_in[0];
    const float* emb    = (const float*)d_in[1];
    float* out = (float*)d_out;
    float* res = out + 1;   // residual scratch; rewritten by k_final_out

    char*   ws       = (char*)d_ws;
    double* loss_acc = (double*)ws;
    int*    acnt     = (int*)(ws + 8);
    float*  wnorm    = (float*)(ws + 16);
    float*  rnorm    = (float*)(ws + 16400);
    int*    idx      = (int*)(ws + 278544);
    int*    ambl     = (int*)(ws + 1327120);
    uint4*  wimg     = (uint4*)(ws + 1589264);
    uint4*  aimg     = (uint4*)(ws + 3686416);
    const size_t need = 3686416 + (size_t)NTOK * DIMD * 2;   // ~35.5 MB
    const int use_img = (ws_size >= need) ? 1 : 0;

    k_wsplit<<<256, 256, 0, stream>>>(emb, wimg, acnt);
    k_pairnorm<<<256, 256, 0, stream>>>(emb, wnorm, NLEV * VOC, loss_acc);
    k_rsplit0<<<1024, 256, 0, stream>>>(latent, aimg, rnorm, use_img);

    for (int l = 0; l < NLEV; ++l) {
        const float* rsrc = l ? (const float*)res : latent;
        const float* W    = emb + (size_t)l * VOC * DIMD;
        int*         idxl = idx + l * NTOK;
        const uint4* wl   = wimg + (size_t)l * 32768;
        if (use_img)
            k_screen<1><<<512, 256, 0, stream>>>(rsrc, aimg, wl, rnorm,
                                                 wnorm + l * VOC, idxl, ambl, acnt);
        else
            k_screen<0><<<512, 256, 0, stream>>>(rsrc, aimg, wl, rnorm,
                                                 wnorm + l * VOC, idxl, ambl, acnt);
        k_rescue<<<2048, 64, 0, stream>>>(rsrc, W, wnorm + l * VOC, ambl, acnt, idxl);
        const int mode = (l < NLEV - 1) ? (use_img ? 3 : 1) : 0;
        k_update<<<1024, 256, 0, stream>>>(rsrc, res, aimg, W, idxl, rnorm,
                                           loss_acc, acnt, mode);
    }
    k_final_out<<<1024, 256, 0, stream>>>(latent, emb, idx, res);
    k_loss_final<<<1, 1, 0, stream>>>(loss_acc, out);
}

// Round 6
// 980.818 us; speedup vs baseline: 1.2784x; 1.2784x over previous
//
#include <hip/hip_runtime.h>

#define NTOK 65536
#define DIMD 256
#define VOC  1024
#define NLEV 4
#define TAU  0.045f   // screened top-2 gap below this -> exact resolution

typedef __attribute__((ext_vector_type(8))) _Float16 f16x8;
typedef __attribute__((ext_vector_type(4))) float f32x4;

// ---------------------------------------------------------------------------
// ws layout:
//   [0]        double loss_acc ; [8] int fcnt ; [12] int pcnt
//   [16]       float  wnorm[NLEV][VOC]        (16 KB)
//   [16400]    float  rnorm[NTOK]             (256 KB)
//   [278544]   int    idx[NLEV][NTOK]         (1 MB)
//   [1327120]  int    flist[NTOK]             (256 KB)  full-rescan tokens
//   [1589264]  uint4  wimg[NLEV*64*512]       (2 MB)    f16 pre-swizzled W
//   [3686416]  uint4  aimg[512*8*512]         (32 MB)   f16 pre-swizzled residual
//   [37240848] int2   plist[NTOK]             (512 KB)  pair-rescue (t, i1|i2<<16)
// (no-img fallback: plist sits at aimg's offset)
// residual fp32 lives in d_out[1:] until k_final_out rewrites it.
// ---------------------------------------------------------------------------

__device__ __forceinline__ int swz4(int ko, int r) {
    return ko ^ (r & 3) ^ ((r >> 2) & 3);
}

__device__ __forceinline__ uint4 cvt8_f16(const float4 x0, const float4 x1) {
    union { f16x8 h; uint4 u; } r;
    r.h[0] = (_Float16)x0.x; r.h[1] = (_Float16)x0.y;
    r.h[2] = (_Float16)x0.z; r.h[3] = (_Float16)x0.w;
    r.h[4] = (_Float16)x1.x; r.h[5] = (_Float16)x1.y;
    r.h[6] = (_Float16)x1.z; r.h[7] = (_Float16)x1.w;
    return r.u;
}

__device__ __forceinline__ void gl_lds16(const uint4* g, uint4* l) {
    __builtin_amdgcn_global_load_lds(
        (const __attribute__((address_space(1))) unsigned*)g,
        (__attribute__((address_space(3))) unsigned*)l, 16, 0, 0);
}

__device__ __forceinline__ void store_img4(uint4* aimg, int t, int lane, float4 v) {
    union { _Float16 h[4]; uint2 u; } p;
    p.h[0] = (_Float16)v.x; p.h[1] = (_Float16)v.y;
    p.h[2] = (_Float16)v.z; p.h[3] = (_Float16)v.w;
    const int r  = t & 127;
    const int dc = lane >> 3, ko = (lane >> 1) & 3, hf = lane & 1;
    uint2* dst = (uint2*)(aimg + ((size_t)(t >> 7) * 8 + dc) * 512
                          + r * 4 + swz4(ko, r)) + hf;
    *dst = p.u;
}

// merge two ascending-sorted triples; keep indices for ranks 1,2
__device__ __forceinline__ void merge3(float& a1, float& a2, float& a3, int& ai1, int& ai2,
                                       float o1, float o2, float o3, int oi1, int oi2)
{
    const bool sw = o1 < a1;
    const float b1 = sw ? o1 : a1; const int bi1 = sw ? oi1 : ai1;
    const float c1 = sw ? a1 : o1; const int ci1 = sw ? ai1 : oi1;
    const float b2 = sw ? o2 : a2; const int bi2 = sw ? oi2 : ai2;
    const float c2 = sw ? a2 : o2;
    const float b3 = sw ? o3 : a3;
    a1 = b1; ai1 = bi1;
    if (c1 < b2) { a2 = c1; ai2 = ci1; a3 = fminf(b2, c2); }
    else         { a2 = b2; ai2 = bi2; a3 = fminf(b3, c1); }
}

// ------------------- pre-convert + pre-swizzle W ---------------------------
__global__ void k_wsplit(const float* __restrict__ emb, uint4* __restrict__ wimg,
                         int* cnts)
{
    if (blockIdx.x == 0 && threadIdx.x == 0) { cnts[0] = 0; cnts[1] = 0; }
    const int chunk = blockIdx.x;          // 256: l*64 + cb*8 + dc
    const int l = chunk >> 6, cb = (chunk >> 3) & 7, dc = chunk & 7;
    #pragma unroll
    for (int i = 0; i < 2; ++i) {
        const int s = threadIdx.x + i * 256;   // 0..511
        const int r = s >> 2, ko = s & 3;
        const float* src = emb + ((size_t)(l * VOC + cb * 128 + r)) * DIMD + dc * 32 + ko * 8;
        const float4 x0 = *reinterpret_cast<const float4*>(src);
        const float4 x1 = *reinterpret_cast<const float4*>(src + 4);
        wimg[(size_t)chunk * 512 + r * 4 + swz4(ko, r)] = cvt8_f16(x0, x1);
    }
}

// ------------------- numpy pairwise sum-of-squares -------------------------
__device__ __forceinline__ float np_pairnorm_row(const float* row, int j)
{
#pragma clang fp contract(off)
    const int half = j >> 3;
    const int jj   = j & 7;
    const float* a = row + half * 128 + jj;
    float r = a[0] * a[0];
    #pragma unroll
    for (int i = 1; i < 16; ++i) {
        const float x  = a[8 * i];
        const float sq = x * x;
        r = r + sq;
    }
    r = r + __shfl_xor(r, 1);
    r = r + __shfl_xor(r, 2);
    r = r + __shfl_xor(r, 4);
    r = r + __shfl_xor(r, 8);
    return r;
}

__global__ void k_pairnorm(const float* src, float* __restrict__ dst,
                           int nrows, double* loss_acc)
{
    if (loss_acc && blockIdx.x == 0 && threadIdx.x == 0) *loss_acc = 0.0;
    const int gtid  = blockIdx.x * blockDim.x + threadIdx.x;
    const int gwave = gtid >> 6;
    const int lane  = threadIdx.x & 63;
    const int nwave = (gridDim.x * blockDim.x) >> 6;
    const int sub   = lane >> 4;
    const int j     = lane & 15;
    for (int r4 = gwave; r4 * 4 < nrows; r4 += nwave) {
        const int row = r4 * 4 + sub;
        const float v = np_pairnorm_row(src + (size_t)row * DIMD, j);
        if (j == 0) dst[row] = v;
    }
}

// ---- level-0: latent -> aimg (optional) + approx rnorm ---------------------
__global__ void k_rsplit0(const float* __restrict__ latent, uint4* __restrict__ aimg,
                          float* __restrict__ rnorm, int write_img)
{
    const int gtid = blockIdx.x * blockDim.x + threadIdx.x;
    const int gw   = gtid >> 6, lane = threadIdx.x & 63;
    const int nw   = (gridDim.x * blockDim.x) >> 6;
    for (int t = gw; t < NTOK; t += nw) {
        const float4 v = reinterpret_cast<const float4*>(latent + (size_t)t * DIMD)[lane];
        float s4 = v.x * v.x + v.y * v.y + v.z * v.z + v.w * v.w;
        #pragma unroll
        for (int off = 32; off; off >>= 1) s4 += __shfl_xor(s4, off);
        if (lane == 0) rnorm[t] = s4;
        if (write_img) store_img4(aimg, t, lane, v);
    }
}

// on-the-fly A conversion for the no-image fallback path
__device__ __forceinline__ void stageA_fly(const float* rsrc, int tok0, int dn,
                                           uint4* dst, int tid)
{
    #pragma unroll
    for (int i = 0; i < 2; ++i) {
        const int s = tid + i * 256, r = s >> 2, ko = s & 3;
        const float* g = rsrc + (size_t)(tok0 + r) * DIMD + dn * 32 + ko * 8;
        dst[r * 4 + swz4(ko, r)] =
            cvt8_f16(*reinterpret_cast<const float4*>(g),
                     *reinterpret_cast<const float4*>(g + 4));
    }
}

// ------------- f16 MFMA screen (single pass, top-3 classify) ----------------
template<int PRESPLIT>
__global__ __launch_bounds__(256, 2)
void k_screen(const float* rsrc, const uint4* __restrict__ aimg,
              const uint4* __restrict__ wimg_l,
              const float* __restrict__ rnorm, const float* __restrict__ wnorml,
              int* __restrict__ idxl, int2* __restrict__ plist,
              int* __restrict__ flist, int* cnts)
{
    __shared__ uint4 ldsA[2][512];   // 16 KB
    __shared__ uint4 ldsB[2][512];   // 16 KB
    __shared__ float tM1[128][2], tM2[128][2], tM3[128][2];
    __shared__ int   tI1[128][2], tI2[128][2];

    const int tid = threadIdx.x, lane = tid & 63, w = tid >> 6;
    const int wm = w >> 1, wn = w & 1;
    const int lr = lane & 15, lg = lane >> 4;
    const int tok0 = blockIdx.x * 128;
    const uint4* ablk = aimg + (size_t)blockIdx.x * (8 * 512);

    float rn[4][4];
    #pragma unroll
    for (int m = 0; m < 4; ++m)
        #pragma unroll
        for (int r = 0; r < 4; ++r)
            rn[m][r] = rnorm[tok0 + wm * 64 + m * 16 + lg * 4 + r];

    float m1[4][4], m2[4][4], m3[4][4]; int i1[4][4], i2[4][4];
    #pragma unroll
    for (int m = 0; m < 4; ++m)
        #pragma unroll
        for (int r = 0; r < 4; ++r) {
            m1[m][r] = 3.0e38f; m2[m][r] = 3.0e38f; m3[m][r] = 3.0e38f;
            i1[m][r] = 0; i2[m][r] = 0;
        }

    f32x4 acc[4][4];

    // prologue: stage phase 0
    if (PRESPLIT) { gl_lds16(ablk + tid, &ldsA[0][tid]); gl_lds16(ablk + tid + 256, &ldsA[0][tid + 256]); }
    else          stageA_fly(rsrc, tok0, 0, &ldsA[0][0], tid);
    gl_lds16(wimg_l + tid, &ldsB[0][tid]);
    gl_lds16(wimg_l + tid + 256, &ldsB[0][tid + 256]);
    __syncthreads();

    for (int p = 0; p < 64; ++p) {
        const int cur = p & 1, nxt = cur ^ 1;
        const int ct = p >> 3, dc = p & 7;
        if (p < 63) {   // stage next phase (flies during compute)
            const int dn = (p + 1) & 7;
            if (PRESPLIT) {
                const uint4* src = ablk + (size_t)dn * 512;
                gl_lds16(src + tid, &ldsA[nxt][tid]);
                gl_lds16(src + tid + 256, &ldsA[nxt][tid + 256]);
            } else {
                stageA_fly(rsrc, tok0, dn, &ldsA[nxt][0], tid);
            }
            const uint4* bs = wimg_l + (size_t)(p + 1) * 512;
            gl_lds16(bs + tid, &ldsB[nxt][tid]);
            gl_lds16(bs + tid + 256, &ldsB[nxt][tid + 256]);
        }
        if (dc == 0) {
            #pragma unroll
            for (int m = 0; m < 4; ++m)
                #pragma unroll
                for (int n = 0; n < 4; ++n) acc[m][n] = (f32x4)0.0f;
        }
        f16x8 af[4];
        #pragma unroll
        for (int m = 0; m < 4; ++m) {
            const int r = wm * 64 + m * 16 + lr;
            af[m] = *reinterpret_cast<const f16x8*>(&ldsA[cur][r * 4 + swz4(lg, r)]);
        }
        #pragma unroll
        for (int n = 0; n < 4; ++n) {
            const int rb = wn * 64 + n * 16 + lr;
            const f16x8 bf = *reinterpret_cast<const f16x8*>(&ldsB[cur][rb * 4 + swz4(lg, rb)]);
            #pragma unroll
            for (int m = 0; m < 4; ++m)
                acc[m][n] = __builtin_amdgcn_mfma_f32_16x16x32_f16(af[m], bf, acc[m][n], 0, 0, 0);
        }
        if (dc == 7) {   // finish this 128-code tile: top-3 update
            #pragma unroll
            for (int n = 0; n < 4; ++n) {
                const int c = ct * 128 + wn * 64 + n * 16 + lr;
                const float wnv = wnorml[c];
                #pragma unroll
                for (int m = 0; m < 4; ++m)
                    #pragma unroll
                    for (int r = 0; r < 4; ++r) {
                        const float s = fmaf(-2.0f, acc[m][n][r], rn[m][r]) + wnv;
                        if (s < m1[m][r]) {
                            m3[m][r] = m2[m][r]; m2[m][r] = m1[m][r]; i2[m][r] = i1[m][r];
                            m1[m][r] = s; i1[m][r] = c;
                        } else if (s < m2[m][r]) {
                            m3[m][r] = m2[m][r]; m2[m][r] = s; i2[m][r] = c;
                        } else if (s < m3[m][r]) {
                            m3[m][r] = s;
                        }
                    }
            }
        }
        __syncthreads();
    }

    // butterfly top-3 merge across the 16 col-lanes, then LDS cross-wave merge
    #pragma unroll
    for (int m = 0; m < 4; ++m)
        #pragma unroll
        for (int r = 0; r < 4; ++r) {
            float a1 = m1[m][r], a2 = m2[m][r], a3 = m3[m][r];
            int ai1 = i1[m][r], ai2 = i2[m][r];
            #pragma unroll
            for (int d = 1; d < 16; d <<= 1) {
                const float o1 = __shfl_xor(a1, d);
                const float o2 = __shfl_xor(a2, d);
                const float o3 = __shfl_xor(a3, d);
                const int  oi1 = __shfl_xor(ai1, d);
                const int  oi2 = __shfl_xor(ai2, d);
                merge3(a1, a2, a3, ai1, ai2, o1, o2, o3, oi1, oi2);
            }
            if (lr == 0) {
                const int t = wm * 64 + m * 16 + lg * 4 + r;
                tM1[t][wn] = a1; tM2[t][wn] = a2; tM3[t][wn] = a3;
                tI1[t][wn] = ai1; tI2[t][wn] = ai2;
            }
        }
    __syncthreads();
    if (tid < 128) {
        float a1 = tM1[tid][0], a2 = tM2[tid][0], a3 = tM3[tid][0];
        int ai1 = tI1[tid][0], ai2 = tI2[tid][0];
        merge3(a1, a2, a3, ai1, ai2,
               tM1[tid][1], tM2[tid][1], tM3[tid][1], tI1[tid][1], tI2[tid][1]);
        const int gt = tok0 + tid;
        idxl[gt] = ai1;
        if (a2 - a1 < TAU) {
            if (a3 - a1 >= TAU) {   // exact winner must be ai1 or ai2
                const int p = atomicAdd(&cnts[1], 1);
                plist[p] = make_int2(gt, ai1 | (ai2 << 16));
            } else {                // rare: full exact rescan
                const int p = atomicAdd(&cnts[0], 1);
                flist[p] = gt;
            }
        }
    }
}

// ------- exact numpy-fp32 compare of the two candidate codes ----------------
__global__ void k_pair_rescue(const float* rsrc, const float* __restrict__ embl,
                              const float* __restrict__ wnorml,
                              const int2* __restrict__ plist, const int* __restrict__ cnts,
                              int* __restrict__ idxl)
{
    __shared__ float rbuf[DIMD];
    const int lane = threadIdx.x;   // blockDim.x == 64
    int cnt = cnts[1]; if (cnt > NTOK) cnt = NTOK;
    for (int k = blockIdx.x; k < cnt; k += gridDim.x) {
        const int2 e = plist[k];
        const int t  = e.x;
        const int c1 = e.y & 0xffff, c2 = (e.y >> 16) & 0xffff;
        reinterpret_cast<float4*>(rbuf)[lane] =
            reinterpret_cast<const float4*>(rsrc + (size_t)t * DIMD)[lane];
        __syncthreads();
        const float rnv = np_pairnorm_row(rbuf, lane & 15);
        const int myc = lane ? c2 : c1;
        float acc = 0.0f;
        if (lane < 2) {
            const float* wr = embl + (size_t)myc * DIMD;
            for (int d = 0; d < DIMD; d += 4) {   // sequential fmaf, d ascending
                const float4 wv = *reinterpret_cast<const float4*>(wr + d);
                acc = fmaf(rbuf[d + 0], wv.x, acc);
                acc = fmaf(rbuf[d + 1], wv.y, acc);
                acc = fmaf(rbuf[d + 2], wv.z, acc);
                acc = fmaf(rbuf[d + 3], wv.w, acc);
            }
        }
        const float s_l = fmaf(-2.0f, acc, rnv) + wnorml[myc];
        const float s2  = __shfl(s_l, 1);
        if (lane == 0) {
            int win;
            if (s_l < s2)      win = c1;
            else if (s2 < s_l) win = c2;
            else               win = min(c1, c2);
            idxl[t] = win;
        }
        __syncthreads();
    }
}

// ------- exact numpy-fp32 full rescan (rare tokens), 4-way code ILP ---------
__global__ void k_full_rescue(const float* rsrc, const float* __restrict__ embl,
                              const float* __restrict__ wnorml,
                              const int* __restrict__ flist, const int* __restrict__ cnts,
                              int* __restrict__ idxl)
{
    __shared__ float rbuf[DIMD];
    const int lane = threadIdx.x;   // blockDim.x == 64
    int cnt = cnts[0]; if (cnt > NTOK) cnt = NTOK;
    for (int k = blockIdx.x; k < cnt; k += gridDim.x) {
        const int t = flist[k];
        reinterpret_cast<float4*>(rbuf)[lane] =
            reinterpret_cast<const float4*>(rsrc + (size_t)t * DIMD)[lane];
        __syncthreads();
        const float rnv = np_pairnorm_row(rbuf, lane & 15);
        float best = 3.0e38f; int besti = 0x7fffffff;
        for (int j = 0; j < 4; ++j) {
            const float* w0 = embl + (size_t)(j * 256 + lane) * DIMD;
            float a0 = 0.f, a1 = 0.f, a2 = 0.f, a3 = 0.f;
            for (int d = 0; d < DIMD; d += 4) {
                const float4 r4 = *reinterpret_cast<const float4*>(&rbuf[d]);
                const float4 v0 = *reinterpret_cast<const float4*>(w0 + d);
                const float4 v1 = *reinterpret_cast<const float4*>(w0 + 64 * DIMD + d);
                const float4 v2 = *reinterpret_cast<const float4*>(w0 + 128 * DIMD + d);
                const float4 v3 = *reinterpret_cast<const float4*>(w0 + 192 * DIMD + d);
                a0 = fmaf(r4.x, v0.x, a0); a0 = fmaf(r4.y, v0.y, a0);
                a0 = fmaf(r4.z, v0.z, a0); a0 = fmaf(r4.w, v0.w, a0);
                a1 = fmaf(r4.x, v1.x, a1); a1 = fmaf(r4.y, v1.y, a1);
                a1 = fmaf(r4.z, v1.z, a1); a1 = fmaf(r4.w, v1.w, a1);
                a2 = fmaf(r4.x, v2.x, a2); a2 = fmaf(r4.y, v2.y, a2);
                a2 = fmaf(r4.z, v2.z, a2); a2 = fmaf(r4.w, v2.w, a2);
                a3 = fmaf(r4.x, v3.x, a3); a3 = fmaf(r4.y, v3.y, a3);
                a3 = fmaf(r4.z, v3.z, a3); a3 = fmaf(r4.w, v3.w, a3);
            }
            float s; int c;
            c = j * 256 + lane;        s = fmaf(-2.0f, a0, rnv) + wnorml[c];
            if (s < best) { best = s; besti = c; }
            c = j * 256 + 64 + lane;   s = fmaf(-2.0f, a1, rnv) + wnorml[c];
            if (s < best) { best = s; besti = c; }
            c = j * 256 + 128 + lane;  s = fmaf(-2.0f, a2, rnv) + wnorml[c];
            if (s < best) { best = s; besti = c; }
            c = j * 256 + 192 + lane;  s = fmaf(-2.0f, a3, rnv) + wnorml[c];
            if (s < best) { best = s; besti = c; }
        }
        #pragma unroll
        for (int off = 32; off > 0; off >>= 1) {
            const float ov = __shfl_down(best, off);
            const int   oi = __shfl_down(besti, off);
            if (ov < best || (ov == best && oi < besti)) { best = ov; besti = oi; }
        }
        if (lane == 0) idxl[t] = besti;
        __syncthreads();
    }
}

// ---- fused: gather code; loss; residual fp32; f16 image; approx rnorm ------
// mode bit0: write res + rnorm (levels 0..2); bit1: write aimg
__global__ void k_update(const float* rsrc, float* res, uint4* __restrict__ aimg,
                         const float* embl, const int* __restrict__ idxl,
                         float* __restrict__ rnorm_out,
                         double* loss_acc, int* cnts, int mode)
{
    if (blockIdx.x == 0 && threadIdx.x == 0) { cnts[0] = 0; cnts[1] = 0; }
    const int gtid = blockIdx.x * blockDim.x + threadIdx.x;
    const int gw   = gtid >> 6, lane = threadIdx.x & 63;
    const int nw   = (gridDim.x * blockDim.x) >> 6;
    float lsum = 0.0f;
    for (int t = gw; t < NTOK; t += nw) {
        const int ci = idxl[t];
        const float4 q = reinterpret_cast<const float4*>(embl + (size_t)ci * DIMD)[lane];
        const float4 r = reinterpret_cast<const float4*>(rsrc + (size_t)t * DIMD)[lane];
        float4 nr;
        nr.x = r.x - q.x; nr.y = r.y - q.y; nr.z = r.z - q.z; nr.w = r.w - q.w;
        const float s4 = nr.x * nr.x + nr.y * nr.y + nr.z * nr.z + nr.w * nr.w;
        lsum += s4;
        if (mode & 1) {
            reinterpret_cast<float4*>(res + (size_t)t * DIMD)[lane] = nr;
            float tk = s4;
            #pragma unroll
            for (int off = 32; off; off >>= 1) tk += __shfl_xor(tk, off);
            if (lane == 0) rnorm_out[t] = tk;
        }
        if (mode & 2) store_img4(aimg, t, lane, nr);
    }
    #pragma unroll
    for (int off = 32; off > 0; off >>= 1) lsum += __shfl_down(lsum, off);
    if (lane == 0) atomicAdd(loss_acc, (double)lsum);
}

__global__ void k_final_out(const float* __restrict__ latent, const float* __restrict__ emb,
                            const int* __restrict__ idx, float* outq)
{
    const int gtid  = blockIdx.x * blockDim.x + threadIdx.x;
    const int gwave = gtid >> 6;
    const int lane  = threadIdx.x & 63;
    const int nwave = (gridDim.x * blockDim.x) >> 6;
    for (int t = gwave; t < NTOK; t += nwave) {
        const float4 q0 = reinterpret_cast<const float4*>(
            emb + ((size_t)0 * VOC + idx[0 * NTOK + t]) * DIMD)[lane];
        const float4 q1 = reinterpret_cast<const float4*>(
            emb + ((size_t)1 * VOC + idx[1 * NTOK + t]) * DIMD)[lane];
        const float4 q2 = reinterpret_cast<const float4*>(
            emb + ((size_t)2 * VOC + idx[2 * NTOK + t]) * DIMD)[lane];
        const float4 q3 = reinterpret_cast<const float4*>(
            emb + ((size_t)3 * VOC + idx[3 * NTOK + t]) * DIMD)[lane];
        const float4 l4 = reinterpret_cast<const float4*>(latent + (size_t)t * DIMD)[lane];
        float4 o;
        { float c = q0.x; c = c + q1.x; c = c + q2.x; c = c + q3.x; o.x = l4.x + (c - l4.x); }
        { float c = q0.y; c = c + q1.y; c = c + q2.y; c = c + q3.y; o.y = l4.y + (c - l4.y); }
        { float c = q0.z; c = c + q1.z; c = c + q2.z; c = c + q3.z; o.z = l4.z + (c - l4.z); }
        { float c = q0.w; c = c + q1.w; c = c + q2.w; c = c + q3.w; o.w = l4.w + (c - l4.w); }
        reinterpret_cast<float4*>(outq + (size_t)t * DIMD)[lane] = o;
    }
}

__global__ void k_loss_final(const double* __restrict__ loss_acc, float* __restrict__ out0)
{
    *out0 = (float)(1.25 * (*loss_acc) / ((double)NTOK * (double)DIMD));
}

extern "C" void kernel_launch(void* const* d_in, const int* in_sizes, int n_in,
                              void* d_out, int out_size, void* d_ws, size_t ws_size,
                              hipStream_t stream)
{
    const float* latent = (const float*)d_in[0];
    const float* emb    = (const float*)d_in[1];
    float* out = (float*)d_out;
    float* res = out + 1;   // residual scratch; rewritten by k_final_out

    char*   ws       = (char*)d_ws;
    double* loss_acc = (double*)ws;
    int*    cnts     = (int*)(ws + 8);       // [0]=full, [1]=pair
    float*  wnorm    = (float*)(ws + 16);
    float*  rnorm    = (float*)(ws + 16400);
    int*    idx      = (int*)(ws + 278544);
    int*    flist    = (int*)(ws + 1327120);
    uint4*  wimg     = (uint4*)(ws + 1589264);
    uint4*  aimg     = (uint4*)(ws + 3686416);
    const size_t img_bytes = (size_t)NTOK * DIMD * 2;               // 32 MB
    const size_t need_img  = 3686416 + img_bytes + (size_t)NTOK * 8;
    const int use_img = (ws_size >= need_img) ? 1 : 0;
    int2* plist = use_img ? (int2*)(ws + 3686416 + img_bytes)
                          : (int2*)(ws + 3686416);

    k_wsplit<<<256, 256, 0, stream>>>(emb, wimg, cnts);
    k_pairnorm<<<256, 256, 0, stream>>>(emb, wnorm, NLEV * VOC, loss_acc);
    k_rsplit0<<<1024, 256, 0, stream>>>(latent, aimg, rnorm, use_img);

    for (int l = 0; l < NLEV; ++l) {
        const float* rsrc = l ? (const float*)res : latent;
        const float* W    = emb + (size_t)l * VOC * DIMD;
        int*         idxl = idx + l * NTOK;
        const uint4* wl   = wimg + (size_t)l * 32768;
        if (use_img)
            k_screen<1><<<512, 256, 0, stream>>>(rsrc, aimg, wl, rnorm,
                                                 wnorm + l * VOC, idxl, plist, flist, cnts);
        else
            k_screen<0><<<512, 256, 0, stream>>>(rsrc, aimg, wl, rnorm,
                                                 wnorm + l * VOC, idxl, plist, flist, cnts);
        k_pair_rescue<<<4096, 64, 0, stream>>>(rsrc, W, wnorm + l * VOC, plist, cnts, idxl);
        k_full_rescue<<<1024, 64, 0, stream>>>(rsrc, W, wnorm + l * VOC, flist, cnts, idxl);
        const int mode = (l < NLEV - 1) ? (use_img ? 3 : 1) : 0;
        k_update<<<1024, 256, 0, stream>>>(rsrc, res, aimg, W, idxl, rnorm,
                                           loss_acc, cnts, mode);
    }
    k_final_out<<<1024, 256, 0, stream>>>(latent, emb, idx, res);
    k_loss_final<<<1, 1, 0, stream>>>(loss_acc, out);
}

// Round 7
// 730.031 us; speedup vs baseline: 1.7176x; 1.3435x over previous
//
#include <hip/hip_runtime.h>

#define NTOK 65536
#define DIMD 256
#define VOC  1024
#define NLEV 4
#define TAU  0.045f   // screened top-2 gap below this -> exact resolution

typedef __attribute__((ext_vector_type(8))) _Float16 f16x8;
typedef __attribute__((ext_vector_type(4))) float f32x4;

// ---------------------------------------------------------------------------
// ws layout (fits proven-available ~3.6 MB):
//   [0]        double loss_acc
//   [8]        int    cnts[8]              (per level: [2l]=full, [2l+1]=pair)
//   [64]       float  wnorm[NLEV][VOC]     (16 KB)
//   [16448]    u16    idx[NLEV][NTOK]      (512 KB)
//   [540736]   int    flist[NTOK]          (256 KB)
//   [802880]   int2   plist[NTOK]          (512 KB)
//   [1327168]  uint4  wimg[NLEV*64*512]    (2 MB)  f16 pre-swizzled W
// residual fp32 lives in d_out[1:] (in-place updated level to level) until
// k_finale rewrites it with the output.
// wimg chunk c=(l*8+cb)*8+dc covers codes cb*128..+128 x k dc*32..+32; row r
// holds 4 granules of 8 f16 at position r*4 + swz4(ko,r).
// ---------------------------------------------------------------------------

__device__ __forceinline__ int swz4(int ko, int r) {
    return ko ^ (r & 3) ^ ((r >> 2) & 3);
}

__device__ __forceinline__ uint4 cvt8_f16_u(const float4 x0, const float4 x1) {
    union { f16x8 h; uint4 u; } r;
    r.h[0] = (_Float16)x0.x; r.h[1] = (_Float16)x0.y;
    r.h[2] = (_Float16)x0.z; r.h[3] = (_Float16)x0.w;
    r.h[4] = (_Float16)x1.x; r.h[5] = (_Float16)x1.y;
    r.h[6] = (_Float16)x1.z; r.h[7] = (_Float16)x1.w;
    return r.u;
}

__device__ __forceinline__ f16x8 cvt8_f16(const float4 x0, const float4 x1) {
    union { f16x8 h; uint4 u; } r;
    r.h[0] = (_Float16)x0.x; r.h[1] = (_Float16)x0.y;
    r.h[2] = (_Float16)x0.z; r.h[3] = (_Float16)x0.w;
    r.h[4] = (_Float16)x1.x; r.h[5] = (_Float16)x1.y;
    r.h[6] = (_Float16)x1.z; r.h[7] = (_Float16)x1.w;
    return r.h;
}

__device__ __forceinline__ void gl_lds16(const uint4* g, uint4* l) {
    __builtin_amdgcn_global_load_lds(
        (const __attribute__((address_space(1))) unsigned*)g,
        (__attribute__((address_space(3))) unsigned*)l, 16, 0, 0);
}

// merge two ascending-sorted triples; keep indices for ranks 1,2
__device__ __forceinline__ void merge3(float& a1, float& a2, float& a3, int& ai1, int& ai2,
                                       float o1, float o2, float o3, int oi1, int oi2)
{
    const bool sw = o1 < a1;
    const float b1 = sw ? o1 : a1; const int bi1 = sw ? oi1 : ai1;
    const float c1 = sw ? a1 : o1; const int ci1 = sw ? ai1 : oi1;
    const float b2 = sw ? o2 : a2; const int bi2 = sw ? oi2 : ai2;
    const float c2 = sw ? a2 : o2;
    const float b3 = sw ? o3 : a3;
    a1 = b1; ai1 = bi1;
    if (c1 < b2) { a2 = c1; ai2 = ci1; a3 = fminf(b2, c2); }
    else         { a2 = b2; ai2 = bi2; a3 = fminf(b3, c1); }
}

// ------------------- pre-convert + pre-swizzle W ---------------------------
__global__ void k_wsplit(const float* __restrict__ emb, uint4* __restrict__ wimg,
                         int* cnts)
{
    if (blockIdx.x == 0 && threadIdx.x < 8) cnts[threadIdx.x] = 0;
    const int chunk = blockIdx.x;          // 256: l*64 + cb*8 + dc
    const int l = chunk >> 6, cb = (chunk >> 3) & 7, dc = chunk & 7;
    #pragma unroll
    for (int i = 0; i < 2; ++i) {
        const int s = threadIdx.x + i * 256;   // 0..511
        const int r = s >> 2, ko = s & 3;
        const float* src = emb + ((size_t)(l * VOC + cb * 128 + r)) * DIMD + dc * 32 + ko * 8;
        const float4 x0 = *reinterpret_cast<const float4*>(src);
        const float4 x1 = *reinterpret_cast<const float4*>(src + 4);
        wimg[(size_t)chunk * 512 + r * 4 + swz4(ko, r)] = cvt8_f16_u(x0, x1);
    }
}

// ------------------- numpy pairwise sum-of-squares -------------------------
__device__ __forceinline__ float np_pairnorm_row(const float* row, int j)
{
#pragma clang fp contract(off)
    const int half = j >> 3;
    const int jj   = j & 7;
    const float* a = row + half * 128 + jj;
    float r = a[0] * a[0];
    #pragma unroll
    for (int i = 1; i < 16; ++i) {
        const float x  = a[8 * i];
        const float sq = x * x;
        r = r + sq;
    }
    r = r + __shfl_xor(r, 1);
    r = r + __shfl_xor(r, 2);
    r = r + __shfl_xor(r, 4);
    r = r + __shfl_xor(r, 8);
    return r;
}

__global__ void k_pairnorm(const float* src, float* __restrict__ dst,
                           int nrows, double* loss_acc)
{
    if (loss_acc && blockIdx.x == 0 && threadIdx.x == 0) *loss_acc = 0.0;
    const int gtid  = blockIdx.x * blockDim.x + threadIdx.x;
    const int gwave = gtid >> 6;
    const int lane  = threadIdx.x & 63;
    const int nwave = (gridDim.x * blockDim.x) >> 6;
    const int sub   = lane >> 4;
    const int j     = lane & 15;
    for (int r4 = gwave; r4 * 4 < nrows; r4 += nwave) {
        const int row = r4 * 4 + sub;
        const float v = np_pairnorm_row(src + (size_t)row * DIMD, j);
        if (j == 0) dst[row] = v;
    }
}

// ---------- stage one 64-code x 256-k B tile (32 KB) into LDS ---------------
__device__ __forceinline__ void stageB(const uint4* wimg_l, uint4* dst, int ct2, int tid)
{
    const int cb = ct2 >> 1, h = ct2 & 1;
    const uint4* base = wimg_l + (size_t)(cb * 8) * 512 + h * 256;
    #pragma unroll
    for (int i = 0; i < 8; ++i) {
        const int f = tid + i * 256;       // 0..2047
        const int j = f >> 8, w = f & 255; // piece (=dc), within-piece
        gl_lds16(base + (size_t)j * 512 + w, dst + f);
    }
}

// ------------- screen: A-in-registers, fused residual update ----------------
// Block: 128 tokens, 4 waves x 32 tokens. 16 phases over 64-code B tiles.
// UPD: rin = r_{l-1}; computes r_l = rin - q[idx_prev], writes res_out,
//      accumulates level-(l-1) loss.  !UPD: rin = latent (level 0).
template<int UPD>
__global__ __launch_bounds__(256, 2)
void k_screen(const float* rin, const float* __restrict__ qemb_prev,
              const unsigned short* __restrict__ idx_prev, float* res_out,
              const uint4* __restrict__ wimg_l, const float* __restrict__ wnorml,
              unsigned short* __restrict__ idxl, int2* __restrict__ plist,
              int* __restrict__ flist, int* cnts_l, double* loss_acc)
{
    __shared__ uint4 ldsB[2][2048];   // 64 KB, double-buffered B tile

    const int tid = threadIdx.x, lane = tid & 63, w = tid >> 6;
    const int lr = lane & 15, lg = lane >> 4;
    const int tok0 = blockIdx.x * 128;
    const int wbase = tok0 + w * 32;

    stageB(wimg_l, ldsB[0], 0, tid);   // issue phase-0 staging early

    // ---- prologue: build A fragments (and fused residual update) ----
    f16x8 af[2][8];
    float lsum = 0.0f;
    #pragma unroll
    for (int m = 0; m < 2; ++m) {
        const int t = wbase + m * 16 + lr;
        const float* rrow = rin + (size_t)t * DIMD;
        const float* qrow = nullptr;
        float* orow = nullptr;
        if (UPD) {
            qrow = qemb_prev + (size_t)idx_prev[t] * DIMD;
            orow = res_out + (size_t)t * DIMD;
        }
        #pragma unroll
        for (int dc = 0; dc < 8; ++dc) {
            const int off = dc * 32 + lg * 8;
            float4 x0 = *reinterpret_cast<const float4*>(rrow + off);
            float4 x1 = *reinterpret_cast<const float4*>(rrow + off + 4);
            if (UPD) {
                const float4 q0 = *reinterpret_cast<const float4*>(qrow + off);
                const float4 q1 = *reinterpret_cast<const float4*>(qrow + off + 4);
                x0.x -= q0.x; x0.y -= q0.y; x0.z -= q0.z; x0.w -= q0.w;
                x1.x -= q1.x; x1.y -= q1.y; x1.z -= q1.z; x1.w -= q1.w;
                lsum += x0.x * x0.x + x0.y * x0.y + x0.z * x0.z + x0.w * x0.w
                      + x1.x * x1.x + x1.y * x1.y + x1.z * x1.z + x1.w * x1.w;
                *reinterpret_cast<float4*>(orow + off)     = x0;
                *reinterpret_cast<float4*>(orow + off + 4) = x1;
            }
            af[m][dc] = cvt8_f16(x0, x1);
        }
    }
    if (UPD) {
        #pragma unroll
        for (int o = 32; o; o >>= 1) lsum += __shfl_down(lsum, o);
        if (lane == 0) atomicAdd(loss_acc, (double)lsum);
    }

    float m1[2][4], m2[2][4], m3[2][4]; int i1[2][4], i2[2][4];
    #pragma unroll
    for (int m = 0; m < 2; ++m)
        #pragma unroll
        for (int r = 0; r < 4; ++r) {
            m1[m][r] = 3.0e38f; m2[m][r] = 3.0e38f; m3[m][r] = 3.0e38f;
            i1[m][r] = 0; i2[m][r] = 0;
        }

    __syncthreads();   // phase-0 staging complete (vmcnt drain)

    // ---- 16 phases over 64-code tiles ----
    for (int p = 0; p < 16; ++p) {
        const int cur = p & 1;
        if (p < 15) stageB(wimg_l, ldsB[cur ^ 1], p + 1, tid);

        float wn[4];
        #pragma unroll
        for (int n = 0; n < 4; ++n) wn[n] = wnorml[p * 64 + n * 16 + lr];

        f32x4 acc[2][4];
        #pragma unroll
        for (int m = 0; m < 2; ++m)
            #pragma unroll
            for (int n = 0; n < 4; ++n) acc[m][n] = (f32x4)0.0f;

        const uint4* bb = &ldsB[cur][0];
        #pragma unroll
        for (int dc = 0; dc < 8; ++dc) {
            #pragma unroll
            for (int n = 0; n < 4; ++n) {
                const int rb = n * 16 + lr;
                const f16x8 bf = *reinterpret_cast<const f16x8*>(
                    &bb[dc * 256 + rb * 4 + swz4(lg, rb)]);
                acc[0][n] = __builtin_amdgcn_mfma_f32_16x16x32_f16(af[0][dc], bf, acc[0][n], 0, 0, 0);
                acc[1][n] = __builtin_amdgcn_mfma_f32_16x16x32_f16(af[1][dc], bf, acc[1][n], 0, 0, 0);
            }
        }
        // top-3 update:  s = wnorm - 2*dot  (rnorm is a per-token constant;
        // it cancels in argmin and in all gap comparisons)
        #pragma unroll
        for (int n = 0; n < 4; ++n) {
            const int c = p * 64 + n * 16 + lr;
            #pragma unroll
            for (int m = 0; m < 2; ++m)
                #pragma unroll
                for (int r = 0; r < 4; ++r) {
                    const float s = fmaf(-2.0f, acc[m][n][r], wn[n]);
                    if (s < m1[m][r]) {
                        m3[m][r] = m2[m][r]; m2[m][r] = m1[m][r]; i2[m][r] = i1[m][r];
                        m1[m][r] = s; i1[m][r] = c;
                    } else if (s < m2[m][r]) {
                        m3[m][r] = m2[m][r]; m2[m][r] = s; i2[m][r] = c;
                    } else if (s < m3[m][r]) {
                        m3[m][r] = s;
                    }
                }
        }
        __syncthreads();
    }

    // ---- butterfly top-3 merge across the 16 col-lanes; direct writeout ----
    #pragma unroll
    for (int m = 0; m < 2; ++m)
        #pragma unroll
        for (int r = 0; r < 4; ++r) {
            float a1 = m1[m][r], a2 = m2[m][r], a3 = m3[m][r];
            int ai1 = i1[m][r], ai2 = i2[m][r];
            #pragma unroll
            for (int d = 1; d < 16; d <<= 1) {
                const float o1 = __shfl_xor(a1, d);
                const float o2 = __shfl_xor(a2, d);
                const float o3 = __shfl_xor(a3, d);
                const int  oi1 = __shfl_xor(ai1, d);
                const int  oi2 = __shfl_xor(ai2, d);
                merge3(a1, a2, a3, ai1, ai2, o1, o2, o3, oi1, oi2);
            }
            if (lr == 0) {
                const int gt = wbase + m * 16 + lg * 4 + r;
                idxl[gt] = (unsigned short)ai1;
                if (a2 - a1 < TAU) {
                    if (a3 - a1 >= TAU) {   // exact winner must be ai1 or ai2
                        const int pp = atomicAdd(&cnts_l[1], 1);
                        plist[pp] = make_int2(gt, ai1 | (ai2 << 16));
                    } else {                // rare: full exact rescan
                        const int pp = atomicAdd(&cnts_l[0], 1);
                        flist[pp] = gt;
                    }
                }
            }
        }
}

// ---- merged exact rescue: blocks [0,1024) pair-compare, [1024,1536) full ---
__global__ void k_rescue(const float* rsrc, const float* __restrict__ embl,
                         const float* __restrict__ wnorml,
                         const int2* __restrict__ plist, const int* __restrict__ flist,
                         const int* __restrict__ cnts_l,
                         unsigned short* __restrict__ idxl)
{
    __shared__ float rbuf[DIMD];
    const int lane = threadIdx.x;   // blockDim.x == 64
    if (blockIdx.x < 1024) {
        int cnt = cnts_l[1]; if (cnt > NTOK) cnt = NTOK;
        for (int k = blockIdx.x; k < cnt; k += 1024) {
            const int2 e = plist[k];
            const int t  = e.x;
            const int c1 = e.y & 0xffff, c2 = (e.y >> 16) & 0xffff;
            reinterpret_cast<float4*>(rbuf)[lane] =
                reinterpret_cast<const float4*>(rsrc + (size_t)t * DIMD)[lane];
            __syncthreads();
            const float rnv = np_pairnorm_row(rbuf, lane & 15);
            const int myc = lane ? c2 : c1;
            float acc = 0.0f;
            if (lane < 2) {
                const float* wr = embl + (size_t)myc * DIMD;
                for (int d = 0; d < DIMD; d += 4) {   // sequential fmaf, d ascending
                    const float4 wv = *reinterpret_cast<const float4*>(wr + d);
                    acc = fmaf(rbuf[d + 0], wv.x, acc);
                    acc = fmaf(rbuf[d + 1], wv.y, acc);
                    acc = fmaf(rbuf[d + 2], wv.z, acc);
                    acc = fmaf(rbuf[d + 3], wv.w, acc);
                }
            }
            const float s_l = fmaf(-2.0f, acc, rnv) + wnorml[myc];
            const float s2  = __shfl(s_l, 1);
            if (lane == 0) {
                int win;
                if (s_l < s2)      win = c1;
                else if (s2 < s_l) win = c2;
                else               win = min(c1, c2);
                idxl[t] = (unsigned short)win;
            }
            __syncthreads();
        }
    } else {
        int cnt = cnts_l[0]; if (cnt > NTOK) cnt = NTOK;
        for (int k = blockIdx.x - 1024; k < cnt; k += 512) {
            const int t = flist[k];
            reinterpret_cast<float4*>(rbuf)[lane] =
                reinterpret_cast<const float4*>(rsrc + (size_t)t * DIMD)[lane];
            __syncthreads();
            const float rnv = np_pairnorm_row(rbuf, lane & 15);
            float best = 3.0e38f; int besti = 0x7fffffff;
            for (int j = 0; j < 4; ++j) {
                const float* w0 = embl + (size_t)(j * 256 + lane) * DIMD;
                float a0 = 0.f, a1 = 0.f, a2 = 0.f, a3 = 0.f;
                for (int d = 0; d < DIMD; d += 4) {
                    const float4 r4 = *reinterpret_cast<const float4*>(&rbuf[d]);
                    const float4 v0 = *reinterpret_cast<const float4*>(w0 + d);
                    const float4 v1 = *reinterpret_cast<const float4*>(w0 + 64 * DIMD + d);
                    const float4 v2 = *reinterpret_cast<const float4*>(w0 + 128 * DIMD + d);
                    const float4 v3 = *reinterpret_cast<const float4*>(w0 + 192 * DIMD + d);
                    a0 = fmaf(r4.x, v0.x, a0); a0 = fmaf(r4.y, v0.y, a0);
                    a0 = fmaf(r4.z, v0.z, a0); a0 = fmaf(r4.w, v0.w, a0);
                    a1 = fmaf(r4.x, v1.x, a1); a1 = fmaf(r4.y, v1.y, a1);
                    a1 = fmaf(r4.z, v1.z, a1); a1 = fmaf(r4.w, v1.w, a1);
                    a2 = fmaf(r4.x, v2.x, a2); a2 = fmaf(r4.y, v2.y, a2);
                    a2 = fmaf(r4.z, v2.z, a2); a2 = fmaf(r4.w, v2.w, a2);
                    a3 = fmaf(r4.x, v3.x, a3); a3 = fmaf(r4.y, v3.y, a3);
                    a3 = fmaf(r4.z, v3.z, a3); a3 = fmaf(r4.w, v3.w, a3);
                }
                float s; int c;
                c = j * 256 + lane;        s = fmaf(-2.0f, a0, rnv) + wnorml[c];
                if (s < best) { best = s; besti = c; }
                c = j * 256 + 64 + lane;   s = fmaf(-2.0f, a1, rnv) + wnorml[c];
                if (s < best) { best = s; besti = c; }
                c = j * 256 + 128 + lane;  s = fmaf(-2.0f, a2, rnv) + wnorml[c];
                if (s < best) { best = s; besti = c; }
                c = j * 256 + 192 + lane;  s = fmaf(-2.0f, a3, rnv) + wnorml[c];
                if (s < best) { best = s; besti = c; }
            }
            #pragma unroll
            for (int off = 32; off > 0; off >>= 1) {
                const float ov = __shfl_down(best, off);
                const int   oi = __shfl_down(besti, off);
                if (ov < best || (ov == best && oi < besti)) { best = ov; besti = oi; }
            }
            if (lane == 0) idxl[t] = (unsigned short)besti;
            __syncthreads();
        }
    }
}

// ---- finale: output (exact code_sum chain) + level-3 loss ------------------
__global__ void k_finale(const float* __restrict__ latent, const float* __restrict__ emb,
                         const unsigned short* __restrict__ idx, float* outq,
                         double* loss_acc)
{
    const int gtid  = blockIdx.x * blockDim.x + threadIdx.x;
    const int gwave = gtid >> 6;
    const int lane  = threadIdx.x & 63;
    const int nwave = (gridDim.x * blockDim.x) >> 6;
    float lsum = 0.0f;
    for (int t = gwave; t < NTOK; t += nwave) {
        const float4 q0 = reinterpret_cast<const float4*>(
            emb + ((size_t)0 * VOC + idx[0 * NTOK + t]) * DIMD)[lane];
        const float4 q1 = reinterpret_cast<const float4*>(
            emb + ((size_t)1 * VOC + idx[1 * NTOK + t]) * DIMD)[lane];
        const float4 q2 = reinterpret_cast<const float4*>(
            emb + ((size_t)2 * VOC + idx[2 * NTOK + t]) * DIMD)[lane];
        const float4 q3 = reinterpret_cast<const float4*>(
            emb + ((size_t)3 * VOC + idx[3 * NTOK + t]) * DIMD)[lane];
        const float4 l4 = reinterpret_cast<const float4*>(latent + (size_t)t * DIMD)[lane];
        float4 o;
        {   // out chain: cs = ((q0+q1)+q2)+q3 ; o = l + (cs - l)
            // loss3 chain: r3 = ((l-q0)-q1)-q2 ; e = q3 - r3
            float c, r3, e;
            c = q0.x; c = c + q1.x; c = c + q2.x; c = c + q3.x; o.x = l4.x + (c - l4.x);
            r3 = l4.x - q0.x; r3 = r3 - q1.x; r3 = r3 - q2.x; e = q3.x - r3; lsum += e * e;
            c = q0.y; c = c + q1.y; c = c + q2.y; c = c + q3.y; o.y = l4.y + (c - l4.y);
            r3 = l4.y - q0.y; r3 = r3 - q1.y; r3 = r3 - q2.y; e = q3.y - r3; lsum += e * e;
            c = q0.z; c = c + q1.z; c = c + q2.z; c = c + q3.z; o.z = l4.z + (c - l4.z);
            r3 = l4.z - q0.z; r3 = r3 - q1.z; r3 = r3 - q2.z; e = q3.z - r3; lsum += e * e;
            c = q0.w; c = c + q1.w; c = c + q2.w; c = c + q3.w; o.w = l4.w + (c - l4.w);
            r3 = l4.w - q0.w; r3 = r3 - q1.w; r3 = r3 - q2.w; e = q3.w - r3; lsum += e * e;
        }
        reinterpret_cast<float4*>(outq + (size_t)t * DIMD)[lane] = o;
    }
    #pragma unroll
    for (int off = 32; off > 0; off >>= 1) lsum += __shfl_down(lsum, off);
    if (lane == 0) atomicAdd(loss_acc, (double)lsum);
}

__global__ void k_loss_final(const double* __restrict__ loss_acc, float* __restrict__ out0)
{
    *out0 = (float)(1.25 * (*loss_acc) / ((double)NTOK * (double)DIMD));
}

extern "C" void kernel_launch(void* const* d_in, const int* in_sizes, int n_in,
                              void* d_out, int out_size, void* d_ws, size_t ws_size,
                              hipStream_t stream)
{
    const float* latent = (const float*)d_in[0];
    const float* emb    = (const float*)d_in[1];
    float* out = (float*)d_out;
    float* res = out + 1;   // residual scratch; rewritten by k_finale

    char*           ws       = (char*)d_ws;
    double*         loss_acc = (double*)ws;
    int*            cnts     = (int*)(ws + 8);
    float*          wnorm    = (float*)(ws + 64);
    unsigned short* idx      = (unsigned short*)(ws + 16448);
    int*            flist    = (int*)(ws + 540736);
    int2*           plist    = (int2*)(ws + 802880);
    uint4*          wimg     = (uint4*)(ws + 1327168);

    k_wsplit<<<256, 256, 0, stream>>>(emb, wimg, cnts);
    k_pairnorm<<<256, 256, 0, stream>>>(emb, wnorm, NLEV * VOC, loss_acc);

    for (int l = 0; l < NLEV; ++l) {
        const float*    W    = emb + (size_t)l * VOC * DIMD;
        unsigned short* idxl = idx + l * NTOK;
        const uint4*    wl   = wimg + (size_t)l * 32768;
        const float*    wnl  = wnorm + l * VOC;
        int*            cl   = cnts + 2 * l;
        if (l == 0)
            k_screen<0><<<512, 256, 0, stream>>>(latent, nullptr, nullptr, nullptr,
                                                 wl, wnl, idxl, plist, flist, cl, loss_acc);
        else
            k_screen<1><<<512, 256, 0, stream>>>((l == 1) ? latent : res,
                                                 emb + (size_t)(l - 1) * VOC * DIMD,
                                                 idx + (l - 1) * NTOK, res,
                                                 wl, wnl, idxl, plist, flist, cl, loss_acc);
        const float* rsrc_l = (l == 0) ? latent : res;
        k_rescue<<<1536, 64, 0, stream>>>(rsrc_l, W, wnl, plist, flist, cl, idxl);
    }
    k_finale<<<1024, 256, 0, stream>>>(latent, emb, idx, res, loss_acc);
    k_loss_final<<<1, 1, 0, stream>>>(loss_acc, out);
}

// Round 8
// 718.111 us; speedup vs baseline: 1.7461x; 1.0166x over previous
//
#include <hip/hip_runtime.h>

#define NTOK 65536
#define DIMD 256
#define VOC  1024
#define NLEV 4
#define TAUP 0.052f   // screened top-2 gap below this -> exact resolution
                      // (= 0.045 f16-screen bound + 2*128ulp key-bucket slack)

typedef __attribute__((ext_vector_type(8))) _Float16 f16x8;
typedef __attribute__((ext_vector_type(4))) float f32x4;

// ---------------------------------------------------------------------------
// ws layout:
//   [0]        double loss_acc
//   [8]        int    cnts[8]              (per level: [2l]=full, [2l+1]=pair)
//   [64]       float  wnorm[NLEV][VOC]     (16 KB)
//   [16448]    u16    idx[NLEV][NTOK]      (512 KB)
//   [540736]   int    flist[NTOK]          (256 KB)
//   [802880]   int2   plist[NTOK]          (512 KB)
//   [1327168]  uint4  wimg[NLEV*64*512]    (2 MB)  f16 pre-swizzled W
// residual fp32 lives in d_out[1:] (in-place updated level to level) until
// k_finale rewrites it with the output.
// wimg chunk c=(l*8+cb)*8+dc covers codes cb*128..+128 x k dc*32..+32; row r
// holds 4 granules of 8 f16 at position r*4 + swz4(ko,r).
// ---------------------------------------------------------------------------

__device__ __forceinline__ int swz4(int ko, int r) {
    return ko ^ (r & 3) ^ ((r >> 2) & 3);
}

__device__ __forceinline__ uint4 cvt8_f16_u(const float4 x0, const float4 x1) {
    union { f16x8 h; uint4 u; } r;
    r.h[0] = (_Float16)x0.x; r.h[1] = (_Float16)x0.y;
    r.h[2] = (_Float16)x0.z; r.h[3] = (_Float16)x0.w;
    r.h[4] = (_Float16)x1.x; r.h[5] = (_Float16)x1.y;
    r.h[6] = (_Float16)x1.z; r.h[7] = (_Float16)x1.w;
    return r.u;
}

__device__ __forceinline__ f16x8 cvt8_f16(const float4 x0, const float4 x1) {
    union { f16x8 h; uint4 u; } r;
    r.h[0] = (_Float16)x0.x; r.h[1] = (_Float16)x0.y;
    r.h[2] = (_Float16)x0.z; r.h[3] = (_Float16)x0.w;
    r.h[4] = (_Float16)x1.x; r.h[5] = (_Float16)x1.y;
    r.h[6] = (_Float16)x1.z; r.h[7] = (_Float16)x1.w;
    return r.h;
}

__device__ __forceinline__ void gl_lds16(const uint4* g, uint4* l) {
    __builtin_amdgcn_global_load_lds(
        (const __attribute__((address_space(1))) unsigned*)g,
        (__attribute__((address_space(3))) unsigned*)l, 16, 0, 0);
}

// monotone float->u32 (ascending), and inverse
__device__ __forceinline__ unsigned f2u(float s) {
    const int b = __float_as_int(s);
    return (unsigned)(b ^ ((b >> 31) | 0x80000000));
}
__device__ __forceinline__ float u2f(unsigned u) {
    const unsigned m = (u & 0x80000000u) ? 0x80000000u : 0xFFFFFFFFu;
    return __uint_as_float(u ^ m);
}
__device__ __forceinline__ unsigned med3u(unsigned a, unsigned b, unsigned c) {
    unsigned d;
    asm("v_med3_u32 %0, %1, %2, %3" : "=v"(d) : "v"(a), "v"(b), "v"(c));
    return d;
}

// merge two ascending u32 triples with (value, idx) lexicographic order;
// keep indices for ranks 1,2
__device__ __forceinline__ void merge3u(unsigned& a1, unsigned& a2, unsigned& a3,
                                        int& ai1, int& ai2,
                                        unsigned o1, unsigned o2, unsigned o3,
                                        int oi1, int oi2)
{
    const bool sw = (o1 < a1) || (o1 == a1 && oi1 < ai1);
    const unsigned b1 = sw ? o1 : a1; const int bi1 = sw ? oi1 : ai1;
    const unsigned c1 = sw ? a1 : o1; const int ci1 = sw ? ai1 : oi1;
    const unsigned b2 = sw ? o2 : a2; const int bi2 = sw ? oi2 : ai2;
    const unsigned c2 = sw ? a2 : o2;
    const unsigned b3 = sw ? o3 : a3;
    a1 = b1; ai1 = bi1;
    if (c1 < b2 || (c1 == b2 && ci1 < bi2)) {
        a2 = c1; ai2 = ci1; a3 = min(b2, c2);
    } else {
        a2 = b2; ai2 = bi2; a3 = min(b3, c1);
    }
}

// ------------------- pre-convert + pre-swizzle W ---------------------------
__global__ void k_wsplit(const float* __restrict__ emb, uint4* __restrict__ wimg,
                         int* cnts)
{
    if (blockIdx.x == 0 && threadIdx.x < 8) cnts[threadIdx.x] = 0;
    const int chunk = blockIdx.x;          // 256: l*64 + cb*8 + dc
    const int l = chunk >> 6, cb = (chunk >> 3) & 7, dc = chunk & 7;
    #pragma unroll
    for (int i = 0; i < 2; ++i) {
        const int s = threadIdx.x + i * 256;   // 0..511
        const int r = s >> 2, ko = s & 3;
        const float* src = emb + ((size_t)(l * VOC + cb * 128 + r)) * DIMD + dc * 32 + ko * 8;
        const float4 x0 = *reinterpret_cast<const float4*>(src);
        const float4 x1 = *reinterpret_cast<const float4*>(src + 4);
        wimg[(size_t)chunk * 512 + r * 4 + swz4(ko, r)] = cvt8_f16_u(x0, x1);
    }
}

// ------------------- numpy pairwise sum-of-squares -------------------------
__device__ __forceinline__ float np_pairnorm_row(const float* row, int j)
{
#pragma clang fp contract(off)
    const int half = j >> 3;
    const int jj   = j & 7;
    const float* a = row + half * 128 + jj;
    float r = a[0] * a[0];
    #pragma unroll
    for (int i = 1; i < 16; ++i) {
        const float x  = a[8 * i];
        const float sq = x * x;
        r = r + sq;
    }
    r = r + __shfl_xor(r, 1);
    r = r + __shfl_xor(r, 2);
    r = r + __shfl_xor(r, 4);
    r = r + __shfl_xor(r, 8);
    return r;
}

__global__ void k_pairnorm(const float* src, float* __restrict__ dst,
                           int nrows, double* loss_acc)
{
    if (loss_acc && blockIdx.x == 0 && threadIdx.x == 0) *loss_acc = 0.0;
    const int gtid  = blockIdx.x * blockDim.x + threadIdx.x;
    const int gwave = gtid >> 6;
    const int lane  = threadIdx.x & 63;
    const int nwave = (gridDim.x * blockDim.x) >> 6;
    const int sub   = lane >> 4;
    const int j     = lane & 15;
    for (int r4 = gwave; r4 * 4 < nrows; r4 += nwave) {
        const int row = r4 * 4 + sub;
        const float v = np_pairnorm_row(src + (size_t)row * DIMD, j);
        if (j == 0) dst[row] = v;
    }
}

// ---------- stage one 32-code x 256-k B tile (16 KB) into LDS ---------------
__device__ __forceinline__ void stageB32(const uint4* wimg_l, uint4* dst, int p, int tid)
{
    const uint4* base = wimg_l + (size_t)(p >> 2) * (8 * 512) + (p & 3) * 128;
    #pragma unroll
    for (int i = 0; i < 4; ++i) {
        const int f = tid + i * 256;        // 0..1023
        const int dc = f >> 7, w = f & 127; // piece, within-piece (row_local*4+swz)
        gl_lds16(base + (size_t)dc * 512 + w, dst + f);
    }
}

// ------------- screen: A-in-registers, fused residual update ----------------
// Block: 64 tokens, 4 waves x 16 tokens. 32 phases over 32-code B tiles.
// Packed-key top-3 ladder (u32 min/med3); pair/full classification with TAUP.
template<int UPD>
__global__ __launch_bounds__(256, 4)
void k_screen(const float* rin, const float* __restrict__ qemb_prev,
              const unsigned short* __restrict__ idx_prev, float* res_out,
              const uint4* __restrict__ wimg_l, const float* __restrict__ wnorml,
              unsigned short* __restrict__ idxl, int2* __restrict__ plist,
              int* __restrict__ flist, int* cnts_l, double* loss_acc)
{
    __shared__ uint4 ldsB[2][1024];   // 32 KB, double-buffered B tile
    __shared__ float ldsW[VOC];       // 4 KB wnorm slice

    const int tid = threadIdx.x, lane = tid & 63, w = tid >> 6;
    const int lr = lane & 15, lg = lane >> 4;
    const int tok0 = blockIdx.x * 64;
    const int wbase = tok0 + w * 16;

    stageB32(wimg_l, ldsB[0], 0, tid);                    // phase-0 B staging
    gl_lds16(reinterpret_cast<const uint4*>(wnorml) + tid,
             reinterpret_cast<uint4*>(ldsW) + tid);       // wnorm -> LDS

    // ---- prologue: build A fragments (and fused residual update) ----
    f16x8 af[8];
    float lsum = 0.0f;
    {
        const int t = wbase + lr;
        const float* rrow = rin + (size_t)t * DIMD;
        const float* qrow = nullptr;
        float* orow = nullptr;
        if (UPD) {
            qrow = qemb_prev + (size_t)idx_prev[t] * DIMD;
            orow = res_out + (size_t)t * DIMD;
        }
        #pragma unroll
        for (int dc = 0; dc < 8; ++dc) {
            const int off = dc * 32 + lg * 8;
            float4 x0 = *reinterpret_cast<const float4*>(rrow + off);
            float4 x1 = *reinterpret_cast<const float4*>(rrow + off + 4);
            if (UPD) {
                const float4 q0 = *reinterpret_cast<const float4*>(qrow + off);
                const float4 q1 = *reinterpret_cast<const float4*>(qrow + off + 4);
                x0.x -= q0.x; x0.y -= q0.y; x0.z -= q0.z; x0.w -= q0.w;
                x1.x -= q1.x; x1.y -= q1.y; x1.z -= q1.z; x1.w -= q1.w;
                lsum += x0.x * x0.x + x0.y * x0.y + x0.z * x0.z + x0.w * x0.w
                      + x1.x * x1.x + x1.y * x1.y + x1.z * x1.z + x1.w * x1.w;
                *reinterpret_cast<float4*>(orow + off)     = x0;
                *reinterpret_cast<float4*>(orow + off + 4) = x1;
            }
            af[dc] = cvt8_f16(x0, x1);
        }
    }
    if (UPD) {
        #pragma unroll
        for (int o = 32; o; o >>= 1) lsum += __shfl_down(lsum, o);
        if (lane == 0) atomicAdd(loss_acc, (double)lsum);
    }

    // packed-key top-3 per r-slot (token = wbase + lg*4 + r)
    unsigned k1[4], k2[4], k3[4];
    #pragma unroll
    for (int r = 0; r < 4; ++r) { k1[r] = 0xFFFFFFFFu; k2[r] = 0xFFFFFFFFu; k3[r] = 0xFFFFFFFFu; }

    __syncthreads();   // phase-0 staging + ldsW ready

    for (int p = 0; p < 32; ++p) {
        const int cur = p & 1;
        if (p < 31) stageB32(wimg_l, ldsB[cur ^ 1], p + 1, tid);

        const float wn0 = ldsW[p * 32 + lr];
        const float wn1 = ldsW[p * 32 + 16 + lr];

        f32x4 acc0 = (f32x4)0.0f, acc1 = (f32x4)0.0f;
        const uint4* bb = &ldsB[cur][0];
        #pragma unroll
        for (int dc = 0; dc < 8; ++dc) {
            const int r0 = lr, r1 = 16 + lr;
            const f16x8 b0 = *reinterpret_cast<const f16x8*>(&bb[dc * 128 + r0 * 4 + swz4(lg, r0)]);
            const f16x8 b1 = *reinterpret_cast<const f16x8*>(&bb[dc * 128 + r1 * 4 + swz4(lg, r1)]);
            acc0 = __builtin_amdgcn_mfma_f32_16x16x32_f16(af[dc], b0, acc0, 0, 0, 0);
            acc1 = __builtin_amdgcn_mfma_f32_16x16x32_f16(af[dc], b1, acc1, 0, 0, 0);
        }
        // ladder: key = orderable(s) with low 6 bits = code>>4 (= p*2+n)
        const unsigned cb0 = (unsigned)(p * 2);
        #pragma unroll
        for (int r = 0; r < 4; ++r) {
            {
                const float s = fmaf(-2.0f, acc0[r], wn0);
                const unsigned key = (f2u(s) & 0xFFFFFFC0u) | cb0;
                const unsigned nk3 = med3u(key, k2[r], k3[r]);
                const unsigned nk2 = med3u(k1[r], key, k2[r]);
                k1[r] = min(k1[r], key); k2[r] = nk2; k3[r] = nk3;
            }
            {
                const float s = fmaf(-2.0f, acc1[r], wn1);
                const unsigned key = (f2u(s) & 0xFFFFFFC0u) | (cb0 + 1);
                const unsigned nk3 = med3u(key, k2[r], k3[r]);
                const unsigned nk2 = med3u(k1[r], key, k2[r]);
                k1[r] = min(k1[r], key); k2[r] = nk2; k3[r] = nk3;
            }
        }
        __syncthreads();
    }

    // ---- unpack, butterfly merge across the 16 lr-lanes, writeout ----
    #pragma unroll
    for (int r = 0; r < 4; ++r) {
        unsigned v1 = k1[r] & 0xFFFFFFC0u, v2 = k2[r] & 0xFFFFFFC0u, v3 = k3[r] & 0xFFFFFFC0u;
        int id1 = (int)((k1[r] & 63u) << 4) | lr;
        int id2 = (int)((k2[r] & 63u) << 4) | lr;
        #pragma unroll
        for (int d = 1; d < 16; d <<= 1) {
            const unsigned o1 = __shfl_xor(v1, d);
            const unsigned o2 = __shfl_xor(v2, d);
            const unsigned o3 = __shfl_xor(v3, d);
            const int     oi1 = __shfl_xor(id1, d);
            const int     oi2 = __shfl_xor(id2, d);
            merge3u(v1, v2, v3, id1, id2, o1, o2, o3, oi1, oi2);
        }
        if (lr == 0) {
            const int gt = wbase + lg * 4 + r;
            idxl[gt] = (unsigned short)id1;
            const float s1 = u2f(v1), s2 = u2f(v2), s3 = u2f(v3);
            if (s2 - s1 < TAUP) {
                if (s3 - s1 >= TAUP) {   // exact winner must be id1 or id2
                    const int pp = atomicAdd(&cnts_l[1], 1);
                    plist[pp] = make_int2(gt, id1 | (id2 << 16));
                } else {                 // rare: full exact rescan
                    const int pp = atomicAdd(&cnts_l[0], 1);
                    flist[pp] = gt;
                }
            }
        }
    }
}

// ---- merged exact rescue: blocks [0,1024) pair-compare, [1024,1536) full ---
__global__ void k_rescue(const float* rsrc, const float* __restrict__ embl,
                         const float* __restrict__ wnorml,
                         const int2* __restrict__ plist, const int* __restrict__ flist,
                         const int* __restrict__ cnts_l,
                         unsigned short* __restrict__ idxl)
{
    __shared__ float rbuf[DIMD];
    const int lane = threadIdx.x;   // blockDim.x == 64
    if (blockIdx.x < 1024) {
        int cnt = cnts_l[1]; if (cnt > NTOK) cnt = NTOK;
        for (int k = blockIdx.x; k < cnt; k += 1024) {
            const int2 e = plist[k];
            const int t  = e.x;
            const int c1 = e.y & 0xffff, c2 = (e.y >> 16) & 0xffff;
            reinterpret_cast<float4*>(rbuf)[lane] =
                reinterpret_cast<const float4*>(rsrc + (size_t)t * DIMD)[lane];
            __syncthreads();
            const float rnv = np_pairnorm_row(rbuf, lane & 15);
            const int myc = lane ? c2 : c1;
            float acc = 0.0f;
            if (lane < 2) {
                const float* wr = embl + (size_t)myc * DIMD;
                for (int d = 0; d < DIMD; d += 4) {   // sequential fmaf, d ascending
                    const float4 wv = *reinterpret_cast<const float4*>(wr + d);
                    acc = fmaf(rbuf[d + 0], wv.x, acc);
                    acc = fmaf(rbuf[d + 1], wv.y, acc);
                    acc = fmaf(rbuf[d + 2], wv.z, acc);
                    acc = fmaf(rbuf[d + 3], wv.w, acc);
                }
            }
            const float s_l = fmaf(-2.0f, acc, rnv) + wnorml[myc];
            const float s2  = __shfl(s_l, 1);
            if (lane == 0) {
                int win;
                if (s_l < s2)      win = c1;
                else if (s2 < s_l) win = c2;
                else               win = min(c1, c2);
                idxl[t] = (unsigned short)win;
            }
            __syncthreads();
        }
    } else {
        int cnt = cnts_l[0]; if (cnt > NTOK) cnt = NTOK;
        for (int k = blockIdx.x - 1024; k < cnt; k += 512) {
            const int t = flist[k];
            reinterpret_cast<float4*>(rbuf)[lane] =
                reinterpret_cast<const float4*>(rsrc + (size_t)t * DIMD)[lane];
            __syncthreads();
            const float rnv = np_pairnorm_row(rbuf, lane & 15);
            float best = 3.0e38f; int besti = 0x7fffffff;
            for (int j = 0; j < 4; ++j) {
                const float* w0 = embl + (size_t)(j * 256 + lane) * DIMD;
                float a0 = 0.f, a1 = 0.f, a2 = 0.f, a3 = 0.f;
                for (int d = 0; d < DIMD; d += 4) {
                    const float4 r4 = *reinterpret_cast<const float4*>(&rbuf[d]);
                    const float4 v0 = *reinterpret_cast<const float4*>(w0 + d);
                    const float4 v1 = *reinterpret_cast<const float4*>(w0 + 64 * DIMD + d);
                    const float4 v2 = *reinterpret_cast<const float4*>(w0 + 128 * DIMD + d);
                    const float4 v3 = *reinterpret_cast<const float4*>(w0 + 192 * DIMD + d);
                    a0 = fmaf(r4.x, v0.x, a0); a0 = fmaf(r4.y, v0.y, a0);
                    a0 = fmaf(r4.z, v0.z, a0); a0 = fmaf(r4.w, v0.w, a0);
                    a1 = fmaf(r4.x, v1.x, a1); a1 = fmaf(r4.y, v1.y, a1);
                    a1 = fmaf(r4.z, v1.z, a1); a1 = fmaf(r4.w, v1.w, a1);
                    a2 = fmaf(r4.x, v2.x, a2); a2 = fmaf(r4.y, v2.y, a2);
                    a2 = fmaf(r4.z, v2.z, a2); a2 = fmaf(r4.w, v2.w, a2);
                    a3 = fmaf(r4.x, v3.x, a3); a3 = fmaf(r4.y, v3.y, a3);
                    a3 = fmaf(r4.z, v3.z, a3); a3 = fmaf(r4.w, v3.w, a3);
                }
                float s; int c;
                c = j * 256 + lane;        s = fmaf(-2.0f, a0, rnv) + wnorml[c];
                if (s < best) { best = s; besti = c; }
                c = j * 256 + 64 + lane;   s = fmaf(-2.0f, a1, rnv) + wnorml[c];
                if (s < best) { best = s; besti = c; }
                c = j * 256 + 128 + lane;  s = fmaf(-2.0f, a2, rnv) + wnorml[c];
                if (s < best) { best = s; besti = c; }
                c = j * 256 + 192 + lane;  s = fmaf(-2.0f, a3, rnv) + wnorml[c];
                if (s < best) { best = s; besti = c; }
            }
            #pragma unroll
            for (int off = 32; off > 0; off >>= 1) {
                const float ov = __shfl_down(best, off);
                const int   oi = __shfl_down(besti, off);
                if (ov < best || (ov == best && oi < besti)) { best = ov; besti = oi; }
            }
            if (lane == 0) idxl[t] = (unsigned short)besti;
            __syncthreads();
        }
    }
}

// ---- finale: output (exact code_sum chain) + level-3 loss ------------------
__global__ void k_finale(const float* __restrict__ latent, const float* __restrict__ emb,
                         const unsigned short* __restrict__ idx, float* outq,
                         double* loss_acc)
{
    const int gtid  = blockIdx.x * blockDim.x + threadIdx.x;
    const int gwave = gtid >> 6;
    const int lane  = threadIdx.x & 63;
    const int nwave = (gridDim.x * blockDim.x) >> 6;
    float lsum = 0.0f;
    for (int t = gwave; t < NTOK; t += nwave) {
        const float4 q0 = reinterpret_cast<const float4*>(
            emb + ((size_t)0 * VOC + idx[0 * NTOK + t]) * DIMD)[lane];
        const float4 q1 = reinterpret_cast<const float4*>(
            emb + ((size_t)1 * VOC + idx[1 * NTOK + t]) * DIMD)[lane];
        const float4 q2 = reinterpret_cast<const float4*>(
            emb + ((size_t)2 * VOC + idx[2 * NTOK + t]) * DIMD)[lane];
        const float4 q3 = reinterpret_cast<const float4*>(
            emb + ((size_t)3 * VOC + idx[3 * NTOK + t]) * DIMD)[lane];
        const float4 l4 = reinterpret_cast<const float4*>(latent + (size_t)t * DIMD)[lane];
        float4 o;
        {
            float c, r3, e;
            c = q0.x; c = c + q1.x; c = c + q2.x; c = c + q3.x; o.x = l4.x + (c - l4.x);
            r3 = l4.x - q0.x; r3 = r3 - q1.x; r3 = r3 - q2.x; e = q3.x - r3; lsum += e * e;
            c = q0.y; c = c + q1.y; c = c + q2.y; c = c + q3.y; o.y = l4.y + (c - l4.y);
            r3 = l4.y - q0.y; r3 = r3 - q1.y; r3 = r3 - q2.y; e = q3.y - r3; lsum += e * e;
            c = q0.z; c = c + q1.z; c = c + q2.z; c = c + q3.z; o.z = l4.z + (c - l4.z);
            r3 = l4.z - q0.z; r3 = r3 - q1.z; r3 = r3 - q2.z; e = q3.z - r3; lsum += e * e;
            c = q0.w; c = c + q1.w; c = c + q2.w; c = c + q3.w; o.w = l4.w + (c - l4.w);
            r3 = l4.w - q0.w; r3 = r3 - q1.w; r3 = r3 - q2.w; e = q3.w - r3; lsum += e * e;
        }
        reinterpret_cast<float4*>(outq + (size_t)t * DIMD)[lane] = o;
    }
    #pragma unroll
    for (int off = 32; off > 0; off >>= 1) lsum += __shfl_down(lsum, off);
    if (lane == 0) atomicAdd(loss_acc, (double)lsum);
}

__global__ void k_loss_final(const double* __restrict__ loss_acc, float* __restrict__ out0)
{
    *out0 = (float)(1.25 * (*loss_acc) / ((double)NTOK * (double)DIMD));
}

extern "C" void kernel_launch(void* const* d_in, const int* in_sizes, int n_in,
                              void* d_out, int out_size, void* d_ws, size_t ws_size,
                              hipStream_t stream)
{
    const float* latent = (const float*)d_in[0];
    const float* emb    = (const float*)d_in[1];
    float* out = (float*)d_out;
    float* res = out + 1;   // residual scratch; rewritten by k_finale

    char*           ws       = (char*)d_ws;
    double*         loss_acc = (double*)ws;
    int*            cnts     = (int*)(ws + 8);
    float*          wnorm    = (float*)(ws + 64);
    unsigned short* idx      = (unsigned short*)(ws + 16448);
    int*            flist    = (int*)(ws + 540736);
    int2*           plist    = (int2*)(ws + 802880);
    uint4*          wimg     = (uint4*)(ws + 1327168);

    k_wsplit<<<256, 256, 0, stream>>>(emb, wimg, cnts);
    k_pairnorm<<<256, 256, 0, stream>>>(emb, wnorm, NLEV * VOC, loss_acc);

    for (int l = 0; l < NLEV; ++l) {
        const float*    W    = emb + (size_t)l * VOC * DIMD;
        unsigned short* idxl = idx + l * NTOK;
        const uint4*    wl   = wimg + (size_t)l * 32768;
        const float*    wnl  = wnorm + l * VOC;
        int*            cl   = cnts + 2 * l;
        if (l == 0)
            k_screen<0><<<1024, 256, 0, stream>>>(latent, nullptr, nullptr, nullptr,
                                                  wl, wnl, idxl, plist, flist, cl, loss_acc);
        else
            k_screen<1><<<1024, 256, 0, stream>>>((l == 1) ? latent : res,
                                                  emb + (size_t)(l - 1) * VOC * DIMD,
                                                  idx + (l - 1) * NTOK, res,
                                                  wl, wnl, idxl, plist, flist, cl, loss_acc);
        const float* rsrc_l = (l == 0) ? latent : res;
        k_rescue<<<1536, 64, 0, stream>>>(rsrc_l, W, wnl, plist, flist, cl, idxl);
    }
    k_finale<<<1024, 256, 0, stream>>>(latent, emb, idx, res, loss_acc);
    k_loss_final<<<1, 1, 0, stream>>>(loss_acc, out);
}